// Round 5
// baseline (24837.704 us; speedup 1.0000x reference)
//
#include <hip/hip_runtime.h>

// Problem constants (from reference)
#define BB    2048
#define TT    100
#define CC    8
#define HD    64
#define HHD   128
#define OO    10
#define MROWS 8      // batch rows per block; grid = 256 blocks = 1 block/CU
#define NTHR  512    // 8 waves/block

// R1: 2 blocks/CU doubled weight refetch -> 35% regression. Reverted.
// R3: register-cached weights: FETCH -> ~0 but dur FLAT. Not memory-bound.
// R4: readlane restructure spilled to scratch (WRITE_SIZE 1KB->1.5GB). Confounded.
// Cross-round invariant: VALU-busy TIME ~3.8ms in every variant; bottom-up cost
// model explains only ~1/3 of the 113k cy/substage. Suspect: LDS float atomicAdd
// lowered to a CAS retry loop (atomicrmw fadd on addrspace(3) f32 only becomes
// ds_add_f32 when denorm flushing allowed) -> dependent ~240cy LDS round-trips
// x retries under 4-way same-address wave contention at ~56 sites/wave/substage.
// R5 (this): EXACT R0 structure, but every LDS atomicAdd -> inline-asm
// ds_add_f32 (native fire-and-forget LDS fp add). Clean A/B vs 18.6ms baseline.

__device__ __forceinline__ float fast_tanh(float x) {
  float e = __expf(2.0f * x);
  return 1.0f - 2.0f / (e + 1.0f);
}

// Native LDS float atomic add. Generic pointers to LDS carry the LDS byte
// offset in their low 32 bits (high half is the shared aperture) on gfx9+.
// __syncthreads() emits s_waitcnt lgkmcnt(0) before s_barrier, which drains
// these (they increment lgkmcnt); "memory" clobber blocks reordering.
__device__ __forceinline__ void ds_fadd(float* p, float v) {
  asm volatile("ds_add_f32 %0, %1"
               :: "v"((unsigned)(unsigned long long)p), "v"(v)
               : "memory");
}

__global__ void zero_out_k(float* o) {
  if (threadIdx.x < 2) o[threadIdx.x] = 0.0f;
}

// Hidden layer slice: rows [rb,rb+4), k in [kb,kb+32), lane cols (l, l+64).
// Weights streamed from global (L2-hot) in 16k chunks; relu applied on read.
__device__ __forceinline__ void hidden_layer(const float* __restrict__ Wg,
                                             const float (*pin)[HHD],
                                             float (*pout)[HHD],
                                             int l, int kb, int rb) {
  float a0[4] = {0.f,0.f,0.f,0.f};
  float a1[4] = {0.f,0.f,0.f,0.f};
#pragma unroll
  for (int h = 0; h < 2; ++h) {
    float wx[16], wy[16];                       // chunk-local, dies at loop end
#pragma unroll
    for (int j = 0; j < 16; ++j) {
      const float* wr = Wg + (kb + 16*h + j) * HHD;
      wx[j] = wr[l];                            // 256B coalesced per wave
      wy[j] = wr[l + 64];
    }
#pragma unroll
    for (int rr = 0; rr < 4; ++rr) {
      const float* pr = &pin[rb + rr][kb + 16*h];
      const float4 h0 = *(const float4*)(pr);       // wave-uniform -> broadcast
      const float4 h1 = *(const float4*)(pr + 4);
      const float4 h2 = *(const float4*)(pr + 8);
      const float4 h3 = *(const float4*)(pr + 12);
      const float hk[16] = {
        fmaxf(h0.x,0.f), fmaxf(h0.y,0.f), fmaxf(h0.z,0.f), fmaxf(h0.w,0.f),
        fmaxf(h1.x,0.f), fmaxf(h1.y,0.f), fmaxf(h1.z,0.f), fmaxf(h1.w,0.f),
        fmaxf(h2.x,0.f), fmaxf(h2.y,0.f), fmaxf(h2.z,0.f), fmaxf(h2.w,0.f),
        fmaxf(h3.x,0.f), fmaxf(h3.y,0.f), fmaxf(h3.z,0.f), fmaxf(h3.w,0.f) };
#pragma unroll
      for (int k = 0; k < 16; ++k) {
        a0[rr] = fmaf(hk[k], wx[k], a0[rr]);
        a1[rr] = fmaf(hk[k], wy[k], a1[rr]);
      }
    }
  }
#pragma unroll
  for (int rr = 0; rr < 4; ++rr) {
    ds_fadd(&pout[rb + rr][l],      a0[rr]);
    ds_fadd(&pout[rb + rr][l + 64], a1[rr]);
  }
}

__global__ void __launch_bounds__(NTHR)
cde_main(const float* __restrict__ coeffs, const int* __restrict__ yy,
         const float* __restrict__ times,
         const float* __restrict__ W_init, const float* __restrict__ b_init,
         const float* __restrict__ W_in,  const float* __restrict__ b_in,
         const float* __restrict__ W_h,   const float* __restrict__ b_h,
         const float* __restrict__ W_out, const float* __restrict__ b_out,
         const float* __restrict__ W_read,const float* __restrict__ b_read,
         float* __restrict__ out)
{
  __shared__ float sZs[MROWS][HD];        // 2KB   stage-input z
  __shared__ float pA [MROWS][HHD];       // 4KB   bias-primed partials, layer A
  __shared__ float p1 [MROWS][HHD];       // 4KB   hidden1
  __shared__ float p2 [MROWS][HHD];       // 4KB   hidden2
  __shared__ float pB [MROWS][576];       // 18KB  big layer, addr = col + (col>>3)
  __shared__ float sDx[MROWS][CC];
  __shared__ float sLog[MROWS][OO];

  const int t    = threadIdx.x;
  const int wv   = t >> 6;        // wave id 0..7
  const int l    = t & 63;        // lane
  const int row0 = blockIdx.x * MROWS;
  // P1-P3 mapping: k-slice q = wv&3, row-group rb = 4*(wv>>2)
  const int q    = wv & 3;
  const int rb   = 4 * (wv >> 2);
  // P4 mapping: k-slice ksl = wv&3 (32k), col-half = wv>>2 (256 cols, 4/lane)
  const int colb = 256 * (wv >> 2) + 4 * l;

  // tiny persistent scalars only (~25 regs total incl addressing)
  const float binx = b_in[l],      biny = b_in[l + 64];
  const float b1x  = b_h[l],       b1y  = b_h[l + 64];
  const float b2x  = b_h[HHD + l], b2y  = b_h[HHD + l + 64];
  const float boutv = b_out[t];

  // ---- z0 ; thread owns (row wv, h=l) for RK state ----
  float z0, kacc = 0.f;
  {
    const float* cf = coeffs + (size_t)(row0 + wv) * (TT*CC);
    float a = b_init[l];
#pragma unroll
    for (int c = 0; c < CC; ++c) a = fmaf(cf[c], W_init[c*HD + l], a);
    z0 = a;
    sZs[wv][l] = a;
  }

  // ---- prime partial buffers with bias ----
  pA[wv][l] = binx;  pA[wv][l + 64] = biny;
  p1[wv][l] = b1x;   p1[wv][l + 64] = b1y;
  p2[wv][l] = b2x;   p2[wv][l + 64] = b2y;
#pragma unroll
  for (int r = 0; r < MROWS; ++r) pB[r][t + (t >> 3)] = boutv;
  __syncthreads();

#pragma unroll 1
  for (int step = 0; step < TT-1; ++step) {
    const float dti = times[step+1] - times[step];
    if (t < 64) {   // sDx readers (P5) are barrier-separated both directions
      const int r = t >> 3, c = t & 7;
      const float* cf = coeffs + (size_t)(row0 + r)*(TT*CC) + step*CC + c;
      sDx[r][c] = (cf[CC] - cf[0]) / dti;
    }

#pragma unroll 1
    for (int s = 0; s < 4; ++s) {
      // ---- P1: layer A. rows [rb,rb+4), k in [16q,16q+16). + prime pB ----
      {
        const int kb = 16 * q;
        float wx[16], wy[16];
#pragma unroll
        for (int j = 0; j < 16; ++j) {
          const float* wr = W_in + (kb + j) * HHD;
          wx[j] = wr[l];
          wy[j] = wr[l + 64];
        }
#pragma unroll
        for (int rr = 0; rr < 4; ++rr) {
          const float* zr = &sZs[rb + rr][kb];
          const float4 za = *(const float4*)(zr);
          const float4 zb = *(const float4*)(zr + 4);
          const float4 zc = *(const float4*)(zr + 8);
          const float4 zd = *(const float4*)(zr + 12);
          const float zk[16] = {za.x, za.y, za.z, za.w, zb.x, zb.y, zb.z, zb.w,
                                zc.x, zc.y, zc.z, zc.w, zd.x, zd.y, zd.z, zd.w};
          float a0 = 0.f, a1 = 0.f;
#pragma unroll
          for (int k = 0; k < 16; ++k) {
            a0 = fmaf(zk[k], wx[k], a0);
            a1 = fmaf(zk[k], wy[k], a1);
          }
          ds_fadd(&pA[rb + rr][l],      a0);
          ds_fadd(&pA[rb + rr][l + 64], a1);
        }
#pragma unroll
        for (int r = 0; r < MROWS; ++r) pB[r][t + (t >> 3)] = boutv;
      }
      __syncthreads();
      // ---- P2: hidden1 (reads pA, relu inline) ----
      hidden_layer(W_h, pA, p1, l, 32*q, rb);
      __syncthreads();
      // ---- P3: hidden2 (reads p1) + rebias pA ----
      hidden_layer(W_h + HHD*HHD, p1, p2, l, 32*q, rb);
      pA[wv][l] = binx;  pA[wv][l + 64] = biny;
      __syncthreads();
      // ---- P4: big layer. k in [32q,32q+32), cols colb..colb+3. + rebias p1 ----
      {
        float acc[MROWS][4];
#pragma unroll
        for (int r = 0; r < MROWS; ++r)
#pragma unroll
          for (int c = 0; c < 4; ++c) acc[r][c] = 0.f;

        const float* wp = W_out + (size_t)(32*q) * (HD*CC) + colb;
#pragma unroll
        for (int kc = 0; kc < 8; ++kc) {
          float4 w4[4];                         // 16 regs, chunk-local
#pragma unroll
          for (int j = 0; j < 4; ++j)
            w4[j] = *(const float4*)(wp + (4*kc + j)*(HD*CC));   // 1KB/wave coalesced
          const int k0 = 32*q + 4*kc;
#pragma unroll
          for (int r = 0; r < MROWS; ++r) {
            const float4 hv = *(const float4*)&p2[r][k0];        // broadcast
            const float hf[4] = { fmaxf(hv.x,0.f), fmaxf(hv.y,0.f),
                                  fmaxf(hv.z,0.f), fmaxf(hv.w,0.f) };
#pragma unroll
            for (int j = 0; j < 4; ++j) {
              acc[r][0] = fmaf(hf[j], w4[j].x, acc[r][0]);
              acc[r][1] = fmaf(hf[j], w4[j].y, acc[r][1]);
              acc[r][2] = fmaf(hf[j], w4[j].z, acc[r][2]);
              acc[r][3] = fmaf(hf[j], w4[j].w, acc[r][3]);
            }
          }
        }
#pragma unroll
        for (int r = 0; r < MROWS; ++r)
#pragma unroll
          for (int c = 0; c < 4; ++c) {
            const int col = colb + c;
            ds_fadd(&pB[r][col + (col >> 3)], acc[r][c]);
          }
        p1[wv][l] = b1x;  p1[wv][l + 64] = b1y;
      }
      __syncthreads();
      // ---- P5: epilogue (tanh, einsum dX, RK) + rebias p2 ----
      {
        const float* pr = &pB[wv][9*l];       // cols 8l..8l+7, stride-9 conflict-free
        const float u0 = pr[0], u1 = pr[1], u2 = pr[2], u3 = pr[3];
        const float u4 = pr[4], u5 = pr[5], u6 = pr[6], u7 = pr[7];
        const float4 d0 = *(const float4*)&sDx[wv][0];   // broadcast
        const float4 d1 = *(const float4*)&sDx[wv][4];
        float g = fast_tanh(u0)*d0.x + fast_tanh(u1)*d0.y
                + fast_tanh(u2)*d0.z + fast_tanh(u3)*d0.w
                + fast_tanh(u4)*d1.x + fast_tanh(u5)*d1.y
                + fast_tanh(u6)*d1.z + fast_tanh(u7)*d1.w;
        if (s == 0)      kacc = g;
        else if (s == 3) kacc += g;
        else             kacc += 2.0f * g;
        float zs;
        if (s == 3) {
          z0 = z0 + dti * (1.0f/6.0f) * kacc;
          zs = z0;
        } else {
          zs = z0 + ((s == 2) ? dti : 0.5f * dti) * g;
        }
        sZs[wv][l] = zs;
        p2[wv][l] = b2x;  p2[wv][l + 64] = b2y;
      }
      __syncthreads();
    } // stages
  }   // steps

  // ---- readout: logits = zT @ W_read + b_read ; loss + accuracy ----
  if (t < MROWS * OO) {
    const int r = t / OO, o = t % OO;
    float a = b_read[o];
#pragma unroll 8
    for (int k = 0; k < HD; ++k) a = fmaf(sZs[r][k], W_read[k*OO + o], a);
    sLog[r][o] = a;
  }
  __syncthreads();
  if (t < 64) {
    float lv = 0.f, cv = 0.f;
    if (t < MROWS) {
      const int r = t;
      float mx = sLog[r][0]; int am = 0;
#pragma unroll
      for (int o = 1; o < OO; ++o) { const float v = sLog[r][o]; if (v > mx) { mx = v; am = o; } }
      float se = 0.f;
#pragma unroll
      for (int o = 0; o < OO; ++o) se += expf(sLog[r][o] - mx);
      const float lse = mx + logf(se);
      const int yr = yy[row0 + r];
      lv = (lse - sLog[r][yr]) * (1.0f / (float)BB);
      cv = (am == yr) ? 1.0f : 0.0f;
    }
    lv += __shfl_xor(lv, 1); lv += __shfl_xor(lv, 2); lv += __shfl_xor(lv, 4);
    cv += __shfl_xor(cv, 1); cv += __shfl_xor(cv, 2); cv += __shfl_xor(cv, 4);
    if (t == 0) { atomicAdd(&out[0], lv); atomicAdd(&out[1], cv); }
  }
}

extern "C" void kernel_launch(void* const* d_in, const int* in_sizes, int n_in,
                              void* d_out, int out_size, void* d_ws, size_t ws_size,
                              hipStream_t stream) {
  const float* coeffs = (const float*)d_in[0];
  const int*   y      = (const int*)  d_in[1];
  const float* times  = (const float*)d_in[2];
  const float* W_init = (const float*)d_in[3];
  const float* b_init = (const float*)d_in[4];
  const float* W_in   = (const float*)d_in[5];
  const float* b_in   = (const float*)d_in[6];
  const float* W_h    = (const float*)d_in[7];
  const float* b_h    = (const float*)d_in[8];
  const float* W_out  = (const float*)d_in[9];
  const float* b_out  = (const float*)d_in[10];
  const float* W_read = (const float*)d_in[11];
  const float* b_read = (const float*)d_in[12];
  float* out = (float*)d_out;

  zero_out_k<<<1, 64, 0, stream>>>(out);   // d_out is poisoned 0xAA before every replay
  cde_main<<<BB/MROWS, NTHR, 0, stream>>>(coeffs, y, times, W_init, b_init,
                                          W_in, b_in, W_h, b_h, W_out, b_out,
                                          W_read, b_read, out);
}